// Round 2
// baseline (384.366 us; speedup 1.0000x reference)
//
#include <hip/hip_runtime.h>
#include <math.h>

namespace {

constexpr int   kB     = 16;
constexpr int   kA     = 65536;
constexpr int   kM     = 32;
constexpr int   kC     = 20;
constexpr float kImg   = 600.0f;
constexpr int   kBlock = 256;

// Block-role split: even blockIdx.x = focal stream, odd = anchor/IoU work.
constexpr int kBBlocks       = 2048;                       // focal-stream blocks
constexpr int kABlocks       = 2048;                       // anchor blocks
constexpr int kNBlocks       = kBBlocks + kABlocks;        // 4096 (ws = 4096*3 floats, same as before)
constexpr int kAnchPerABlock = 2 * kBlock;                 // 512 anchors per A-block (2/thread)
constexpr int kABlocksPerBatch = kA / kAnchPerABlock;      // 128
constexpr int kTotalF4       = kB * kA * kC / 4;           // 5,242,880 float4s of cls_preds
constexpr int kStreamThreads = kBBlocks * kBlock;          // 524,288
constexpr int kF4PerThread   = kTotalF4 / kStreamThreads;  // 10 (exact)

__device__ __forceinline__ float smooth_l1(float d) {
    float ad = fabsf(d);
    return ad < 1.0f ? 0.5f * d * d : ad - 0.5f;
}

// f0(x) = sigmoid(x)^2 * softplus(x)  ==  (1-pt)^2 * bce for a t=0 logit.
// The t=1 case is f0(-x). Target-free: lets the 21M-element pass stream.
__device__ __forceinline__ float focal0(float x) {
    float e   = __expf(-fabsf(x));
    float r   = __builtin_amdgcn_rcpf(1.0f + e);
    float sig = (x >= 0.0f) ? r : e * r;                 // sigmoid(x)
    float sp  = __logf(1.0f + e) + fmaxf(x, 0.0f);       // softplus(x)
    return sig * sig * sp;
}

__global__ __launch_bounds__(kBlock, 6) void retina_main(
    const float* __restrict__ loc_preds,   // [B, A, 4]
    const float* __restrict__ cls_preds,   // [B, A, C]
    const float* __restrict__ iou_boxes,   // [A, 4] xywh
    const float* __restrict__ targets,     // [B*M, 6]
    float* __restrict__ partial)           // [kNBlocks][3]
{
    __shared__ float4 sbox[kM];    // x1, y1, x2+1, y2+1 (pixels)
    __shared__ float4 sxywh[kM];   // cx, cy, w, h (pixels)
    __shared__ float  sarea[kM];   // target area (+1 convention)
    __shared__ int    slab[kM];
    __shared__ float  sred[3][kBlock / 64];

    float loc_sum = 0.0f, cls_sum = 0.0f, npos = 0.0f;

    const int bid = blockIdx.x;

    if (bid & 1) {
        // ================= anchor role: IoU argmax, loc loss, focal corrections ======
        const int j  = bid >> 1;                         // [0, 2048)
        const int b  = j / kABlocksPerBatch;             // batch
        const int ab = (j & (kABlocksPerBatch - 1)) * kAnchPerABlock;

        if (threadIdx.x < kM) {
            const float* t = targets + ((size_t)(b * kM + threadIdx.x)) * 6;
            float cx = t[2] * kImg, cy = t[3] * kImg;
            float w  = t[4] * kImg, h  = t[5] * kImg;
            float x1  = cx - w * 0.5f,        y1  = cy - h * 0.5f;
            float x2p = cx + w * 0.5f + 1.0f, y2p = cy + h * 0.5f + 1.0f;
            sbox[threadIdx.x]  = make_float4(x1, y1, x2p, y2p);
            sxywh[threadIdx.x] = make_float4(cx, cy, w, h);
            sarea[threadIdx.x] = (x2p - x1) * (y2p - y1);
            slab[threadIdx.x]  = (int)t[1];
        }
        __syncthreads();

        for (int k = 0; k < 2; ++k) {
            const int a = ab + k * kBlock + threadIdx.x;
            const float4 an = *(const float4*)(iou_boxes + (size_t)a * 4);

            const float ax1  = an.x - an.z * 0.5f;
            const float ay1  = an.y - an.w * 0.5f;
            const float ax2p = an.x + an.z * 0.5f + 1.0f;
            const float ay2p = an.y + an.w * 0.5f + 1.0f;
            const float aarea = (ax2p - ax1) * (ay2p - ay1);

            float best = -1.0f;
            int   mid  = 0;
#pragma unroll
            for (int m = 0; m < kM; ++m) {
                float4 q = sbox[m];
                float lx = fmaxf(ax1,  q.x);
                float ly = fmaxf(ay1,  q.y);
                float rx = fminf(ax2p, q.z);
                float ry = fminf(ay2p, q.w);
                float w  = fmaxf(rx - lx, 0.0f);
                float h  = fmaxf(ry - ly, 0.0f);
                float inter = w * h;
                float uni   = aarea + sarea[m] - inter;
                float iou   = inter * __builtin_amdgcn_rcpf(uni);
                if (iou > best) { best = iou; mid = m; }
            }

            const bool pos = best >= 0.5f;
            const bool ign = (best > 0.4f) && !pos;

            if (pos) {
                npos += 1.0f;
                // exec-masked: only positive lanes fetch their loc row (~5% of 16.7 MB)
                const float4 lp = *(const float4*)(loc_preds + ((size_t)b * kA + a) * 4);
                float4 mb = sxywh[mid];
                float ltx = (mb.x - an.x) * __builtin_amdgcn_rcpf(an.z);
                float lty = (mb.y - an.y) * __builtin_amdgcn_rcpf(an.w);
                float ltw = __logf(mb.z * __builtin_amdgcn_rcpf(an.z));
                float lth = __logf(mb.w * __builtin_amdgcn_rcpf(an.w));
                loc_sum += smooth_l1(lp.x - ltx) + smooth_l1(lp.y - lty) +
                           smooth_l1(lp.z - ltw) + smooth_l1(lp.w - lth);
                // focal correction for the target class: swap 0.75*f0(x) -> 0.25*f0(-x)
                const int   c = slab[mid];
                const float x = cls_preds[((size_t)b * kA + a) * kC + c];
                cls_sum += 0.25f * focal0(-x) - 0.75f * focal0(x);
            } else if (ign) {
                // ignored anchor contributes 0: subtract the stream's f0 over its row
                const float4* row = (const float4*)(cls_preds + ((size_t)b * kA + a) * kC);
                float s = 0.0f;
#pragma unroll
                for (int i = 0; i < kC / 4; ++i) {
                    float4 v = row[i];
                    s += focal0(v.x) + focal0(v.y) + focal0(v.z) + focal0(v.w);
                }
                cls_sum -= 0.75f * s;
            }
        }
    } else {
        // ================= focal stream role: target-free sum of f0 over cls_preds ====
        const int idx = bid >> 1;                        // [0, 2048)
        const float4* cp = (const float4*)cls_preds;
        const int t0 = idx * kBlock + threadIdx.x;       // [0, 524288)
        float csum = 0.0f;
#pragma unroll
        for (int i = 0; i < kF4PerThread; ++i) {
            float4 v = cp[t0 + i * kStreamThreads];      // wave-contiguous 1 KiB loads
            csum += focal0(v.x) + focal0(v.y) + focal0(v.z) + focal0(v.w);
        }
        cls_sum = 0.75f * csum;
    }

    // ---- Reduce: wave shuffle -> LDS -> per-block partial (no atomics) ----
#pragma unroll
    for (int off = 32; off > 0; off >>= 1) {
        loc_sum += __shfl_down(loc_sum, off);
        cls_sum += __shfl_down(cls_sum, off);
        npos    += __shfl_down(npos, off);
    }
    const int lane = threadIdx.x & 63;
    const int wid  = threadIdx.x >> 6;
    if (lane == 0) {
        sred[0][wid] = loc_sum;
        sred[1][wid] = cls_sum;
        sred[2][wid] = npos;
    }
    __syncthreads();
    if (threadIdx.x == 0) {
        float l = 0.0f, c = 0.0f, n = 0.0f;
#pragma unroll
        for (int i = 0; i < kBlock / 64; ++i) {
            l += sred[0][i]; c += sred[1][i]; n += sred[2][i];
        }
        partial[3 * bid + 0] = l;
        partial[3 * bid + 1] = c;
        partial[3 * bid + 2] = n;
    }
}

__global__ __launch_bounds__(1024) void retina_final(
    const float* __restrict__ partial, float* __restrict__ out)
{
    __shared__ float s[3][16];
    float l = 0.0f, c = 0.0f, n = 0.0f;
    for (int i = threadIdx.x; i < kNBlocks; i += 1024) {
        l += partial[3 * i + 0];
        c += partial[3 * i + 1];
        n += partial[3 * i + 2];
    }
#pragma unroll
    for (int off = 32; off > 0; off >>= 1) {
        l += __shfl_down(l, off);
        c += __shfl_down(c, off);
        n += __shfl_down(n, off);
    }
    const int lane = threadIdx.x & 63;
    const int wid  = threadIdx.x >> 6;
    if (lane == 0) { s[0][wid] = l; s[1][wid] = c; s[2][wid] = n; }
    __syncthreads();
    if (threadIdx.x == 0) {
        float L = 0.0f, C = 0.0f, N = 0.0f;
#pragma unroll
        for (int i = 0; i < 16; ++i) { L += s[0][i]; C += s[1][i]; N += s[2][i]; }
        float np  = fmaxf(1.0f, N);
        float inv = 1.0f / np;
        out[0] = (L + C) * inv;
        out[1] = L * inv;
        out[2] = C * inv;
    }
}

}  // namespace

extern "C" void kernel_launch(void* const* d_in, const int* in_sizes, int n_in,
                              void* d_out, int out_size, void* d_ws, size_t ws_size,
                              hipStream_t stream) {
    const float* loc_preds = (const float*)d_in[0];
    const float* cls_preds = (const float*)d_in[1];
    const float* iou_boxes = (const float*)d_in[2];
    const float* targets   = (const float*)d_in[3];
    float* out     = (float*)d_out;
    float* partial = (float*)d_ws;   // 4096*3 floats, fully overwritten each call

    retina_main<<<dim3(kNBlocks), kBlock, 0, stream>>>(loc_preds, cls_preds, iou_boxes, targets, partial);
    retina_final<<<1, 1024, 0, stream>>>(partial, out);
}

// Round 4
// 192.932 us; speedup vs baseline: 1.9922x; 1.9922x over previous
//
#include <hip/hip_runtime.h>
#include <math.h>

namespace {

constexpr int   kB     = 16;
constexpr int   kA     = 65536;
constexpr int   kM     = 32;
constexpr int   kC     = 20;
constexpr float kImg   = 600.0f;
constexpr int   kBlock = 256;

// Block-role split: even blockIdx.x = focal stream, odd = anchor/IoU work.
constexpr int kBBlocks       = 2048;                       // focal-stream blocks
constexpr int kABlocks       = 2048;                       // anchor blocks
constexpr int kNBlocks       = kBBlocks + kABlocks;        // 4096 (ws = 4096*3 floats, same as before)
constexpr int kAnchPerABlock = 2 * kBlock;                 // 512 anchors per A-block (2/thread)
constexpr int kABlocksPerBatch = kA / kAnchPerABlock;      // 128
constexpr int kTotalF4       = kB * kA * kC / 4;           // 5,242,880 float4s of cls_preds
constexpr int kStreamThreads = kBBlocks * kBlock;          // 524,288
constexpr int kF4PerThread   = kTotalF4 / kStreamThreads;  // 10 (exact)

__device__ __forceinline__ float smooth_l1(float d) {
    float ad = fabsf(d);
    return ad < 1.0f ? 0.5f * d * d : ad - 0.5f;
}

// f0(x) = sigmoid(x)^2 * softplus(x)  ==  (1-pt)^2 * bce for a t=0 logit.
// The t=1 case is f0(-x). Target-free: lets the 21M-element pass stream.
__device__ __forceinline__ float focal0(float x) {
    float e   = __expf(-fabsf(x));
    float r   = __builtin_amdgcn_rcpf(1.0f + e);
    float sig = (x >= 0.0f) ? r : e * r;                 // sigmoid(x)
    float sp  = __logf(1.0f + e) + fmaxf(x, 0.0f);       // softplus(x)
    return sig * sig * sp;
}

// NOTE: no min-waves arg! Round-2 lesson: ",6" capped VGPRs at 40 and the
// 10-deep float4 load pipeline spilled to scratch (359 MB WRITE_SIZE, 5.5x).
__global__ __launch_bounds__(kBlock) void retina_main(
    const float* __restrict__ loc_preds,   // [B, A, 4]
    const float* __restrict__ cls_preds,   // [B, A, C]
    const float* __restrict__ iou_boxes,   // [A, 4] xywh
    const float* __restrict__ targets,     // [B*M, 6]
    float* __restrict__ partial)           // [kNBlocks][3]
{
    __shared__ float4 sbox[kM];    // x1, y1, x2+1, y2+1 (pixels)
    __shared__ float4 sxywh[kM];   // cx, cy, w, h (pixels)
    __shared__ float  sarea[kM];   // target area (+1 convention)
    __shared__ int    slab[kM];
    __shared__ float  sred[3][kBlock / 64];

    float loc_sum = 0.0f, cls_sum = 0.0f, npos = 0.0f;

    const int bid = blockIdx.x;

    if (bid & 1) {
        // ================= anchor role: IoU argmax, loc loss, focal corrections ======
        const int j  = bid >> 1;                         // [0, 2048)
        const int b  = j / kABlocksPerBatch;             // batch
        const int ab = (j & (kABlocksPerBatch - 1)) * kAnchPerABlock;

        if (threadIdx.x < kM) {
            const float* t = targets + ((size_t)(b * kM + threadIdx.x)) * 6;
            float cx = t[2] * kImg, cy = t[3] * kImg;
            float w  = t[4] * kImg, h  = t[5] * kImg;
            float x1  = cx - w * 0.5f,        y1  = cy - h * 0.5f;
            float x2p = cx + w * 0.5f + 1.0f, y2p = cy + h * 0.5f + 1.0f;
            sbox[threadIdx.x]  = make_float4(x1, y1, x2p, y2p);
            sxywh[threadIdx.x] = make_float4(cx, cy, w, h);
            sarea[threadIdx.x] = (x2p - x1) * (y2p - y1);
            slab[threadIdx.x]  = (int)t[1];
        }
        __syncthreads();

        for (int k = 0; k < 2; ++k) {
            const int a = ab + k * kBlock + threadIdx.x;
            const float4 an = *(const float4*)(iou_boxes + (size_t)a * 4);

            const float ax1  = an.x - an.z * 0.5f;
            const float ay1  = an.y - an.w * 0.5f;
            const float ax2p = an.x + an.z * 0.5f + 1.0f;
            const float ay2p = an.y + an.w * 0.5f + 1.0f;
            const float aarea = (ax2p - ax1) * (ay2p - ay1);

            float best = -1.0f;
            int   mid  = 0;
#pragma unroll
            for (int m = 0; m < kM; ++m) {
                float4 q = sbox[m];
                float lx = fmaxf(ax1,  q.x);
                float ly = fmaxf(ay1,  q.y);
                float rx = fminf(ax2p, q.z);
                float ry = fminf(ay2p, q.w);
                float w  = fmaxf(rx - lx, 0.0f);
                float h  = fmaxf(ry - ly, 0.0f);
                float inter = w * h;
                float uni   = aarea + sarea[m] - inter;
                float iou   = inter * __builtin_amdgcn_rcpf(uni);
                if (iou > best) { best = iou; mid = m; }
            }

            const bool pos = best >= 0.5f;
            const bool ign = (best > 0.4f) && !pos;

            if (pos) {
                npos += 1.0f;
                // exec-masked: only positive lanes fetch their loc row (~5% of 16.7 MB)
                const float4 lp = *(const float4*)(loc_preds + ((size_t)b * kA + a) * 4);
                float4 mb = sxywh[mid];
                float ltx = (mb.x - an.x) * __builtin_amdgcn_rcpf(an.z);
                float lty = (mb.y - an.y) * __builtin_amdgcn_rcpf(an.w);
                float ltw = __logf(mb.z * __builtin_amdgcn_rcpf(an.z));
                float lth = __logf(mb.w * __builtin_amdgcn_rcpf(an.w));
                loc_sum += smooth_l1(lp.x - ltx) + smooth_l1(lp.y - lty) +
                           smooth_l1(lp.z - ltw) + smooth_l1(lp.w - lth);
                // focal correction for the target class: swap 0.75*f0(x) -> 0.25*f0(-x)
                const int   c = slab[mid];
                const float x = cls_preds[((size_t)b * kA + a) * kC + c];
                cls_sum += 0.25f * focal0(-x) - 0.75f * focal0(x);
            } else if (ign) {
                // ignored anchor contributes 0: subtract the stream's f0 over its row
                const float4* row = (const float4*)(cls_preds + ((size_t)b * kA + a) * kC);
                float s = 0.0f;
#pragma unroll
                for (int i = 0; i < kC / 4; ++i) {
                    float4 v = row[i];
                    s += focal0(v.x) + focal0(v.y) + focal0(v.z) + focal0(v.w);
                }
                cls_sum -= 0.75f * s;
            }
        }
    } else {
        // ================= focal stream role: target-free sum of f0 over cls_preds ====
        const int idx = bid >> 1;                        // [0, 2048)
        const float4* cp = (const float4*)cls_preds;
        const int t0 = idx * kBlock + threadIdx.x;       // [0, 524288)
        float csum = 0.0f;
#pragma unroll
        for (int i = 0; i < kF4PerThread; ++i) {
            float4 v = cp[t0 + i * kStreamThreads];      // wave-contiguous 1 KiB loads
            csum += focal0(v.x) + focal0(v.y) + focal0(v.z) + focal0(v.w);
        }
        cls_sum = 0.75f * csum;
    }

    // ---- Reduce: wave shuffle -> LDS -> per-block partial (no atomics) ----
#pragma unroll
    for (int off = 32; off > 0; off >>= 1) {
        loc_sum += __shfl_down(loc_sum, off);
        cls_sum += __shfl_down(cls_sum, off);
        npos    += __shfl_down(npos, off);
    }
    const int lane = threadIdx.x & 63;
    const int wid  = threadIdx.x >> 6;
    if (lane == 0) {
        sred[0][wid] = loc_sum;
        sred[1][wid] = cls_sum;
        sred[2][wid] = npos;
    }
    __syncthreads();
    if (threadIdx.x == 0) {
        float l = 0.0f, c = 0.0f, n = 0.0f;
#pragma unroll
        for (int i = 0; i < kBlock / 64; ++i) {
            l += sred[0][i]; c += sred[1][i]; n += sred[2][i];
        }
        partial[3 * bid + 0] = l;
        partial[3 * bid + 1] = c;
        partial[3 * bid + 2] = n;
    }
}

__global__ __launch_bounds__(1024) void retina_final(
    const float* __restrict__ partial, float* __restrict__ out)
{
    __shared__ float s[3][16];
    float l = 0.0f, c = 0.0f, n = 0.0f;
    for (int i = threadIdx.x; i < kNBlocks; i += 1024) {
        l += partial[3 * i + 0];
        c += partial[3 * i + 1];
        n += partial[3 * i + 2];
    }
#pragma unroll
    for (int off = 32; off > 0; off >>= 1) {
        l += __shfl_down(l, off);
        c += __shfl_down(c, off);
        n += __shfl_down(n, off);
    }
    const int lane = threadIdx.x & 63;
    const int wid  = threadIdx.x >> 6;
    if (lane == 0) { s[0][wid] = l; s[1][wid] = c; s[2][wid] = n; }
    __syncthreads();
    if (threadIdx.x == 0) {
        float L = 0.0f, C = 0.0f, N = 0.0f;
#pragma unroll
        for (int i = 0; i < 16; ++i) { L += s[0][i]; C += s[1][i]; N += s[2][i]; }
        float np  = fmaxf(1.0f, N);
        float inv = 1.0f / np;
        out[0] = (L + C) * inv;
        out[1] = L * inv;
        out[2] = C * inv;
    }
}

}  // namespace

extern "C" void kernel_launch(void* const* d_in, const int* in_sizes, int n_in,
                              void* d_out, int out_size, void* d_ws, size_t ws_size,
                              hipStream_t stream) {
    const float* loc_preds = (const float*)d_in[0];
    const float* cls_preds = (const float*)d_in[1];
    const float* iou_boxes = (const float*)d_in[2];
    const float* targets   = (const float*)d_in[3];
    float* out     = (float*)d_out;
    float* partial = (float*)d_ws;   // 4096*3 floats, fully overwritten each call

    retina_main<<<dim3(kNBlocks), kBlock, 0, stream>>>(loc_preds, cls_preds, iou_boxes, targets, partial);
    retina_final<<<1, 1024, 0, stream>>>(partial, out);
}

// Round 5
// 150.306 us; speedup vs baseline: 2.5572x; 1.2836x over previous
//
#include <hip/hip_runtime.h>
#include <math.h>

namespace {

constexpr int   kB     = 16;
constexpr int   kA     = 65536;
constexpr int   kM     = 32;
constexpr int   kC     = 20;
constexpr float kImg   = 600.0f;
constexpr int   kBlock = 256;
constexpr int   kF4PerThread = kC / 4;          // 5 float4s per thread (block slab / 256)
constexpr int   kGridX = kA / kBlock;           // 256
constexpr int   kNBlocks = kGridX * kB;         // 4096 (ws = 4096*3 floats)

__device__ __forceinline__ float smooth_l1(float d) {
    float ad = fabsf(d);
    return ad < 1.0f ? 0.5f * d * d : ad - 0.5f;
}

// f0(x) = sigmoid(x)^2 * softplus(x)  ==  w/alpha * bce for a t=0 logit.
// t=1 case is f0(-x). Target-free, so the focal pass needs no per-class logic.
__device__ __forceinline__ float focal0(float x) {
    float e   = __expf(-fabsf(x));
    float r   = __builtin_amdgcn_rcpf(1.0f + e);
    float sig = (x >= 0.0f) ? r : e * r;                 // sigmoid(x)
    float sp  = __logf(1.0f + e) + fmaxf(x, 0.0f);       // softplus(x)
    return sig * sig * sp;
}

// Round-2 lesson: no min-waves arg (",6" capped VGPR=40 -> 359 MB scratch spill).
// Round-4 lesson: uniform blocks beat an even/odd role split (divergent ign-row
// re-reads + VGPR 128 occupancy cliff made the split 1.7x SLOWER than baseline).
__global__ __launch_bounds__(kBlock) void retina_main(
    const float* __restrict__ loc_preds,   // [B, A, 4]
    const float* __restrict__ cls_preds,   // [B, A, C]
    const float* __restrict__ iou_boxes,   // [A, 4] xywh
    const float* __restrict__ targets,     // [B*M, 6]
    float* __restrict__ partial)           // [kNBlocks][3]
{
    __shared__ float4 sbox[kM];    // x1, y1, x2+1, y2+1 (pixels)
    __shared__ float4 sxywh[kM];   // cx, cy, w, h (pixels)
    __shared__ float  sarea[kM];   // target area (+1 convention)
    __shared__ int    slab[kM];
    __shared__ float  slive[kBlock];  // per-anchor: 0 if ignored, else 1
    __shared__ float  sred[3][kBlock / 64];

    const int b  = blockIdx.y;
    const int ab = blockIdx.x * kBlock;   // block's first anchor
    const int a  = ab + threadIdx.x;

    if (threadIdx.x < kM) {
        const float* t = targets + ((size_t)(b * kM + threadIdx.x)) * 6;
        float cx = t[2] * kImg, cy = t[3] * kImg;
        float w  = t[4] * kImg, h  = t[5] * kImg;
        float x1  = cx - w * 0.5f,        y1  = cy - h * 0.5f;
        float x2p = cx + w * 0.5f + 1.0f, y2p = cy + h * 0.5f + 1.0f;
        sbox[threadIdx.x]  = make_float4(x1, y1, x2p, y2p);
        sxywh[threadIdx.x] = make_float4(cx, cy, w, h);
        sarea[threadIdx.x] = (x2p - x1) * (y2p - y1);
        slab[threadIdx.x]  = (int)t[1];
    }

    // Anchor row: independent of LDS, issue before the barrier.
    const float4 an = *(const float4*)(iou_boxes + (size_t)a * 4);

    __syncthreads();

    // Hoist the phase-2 slab loads HERE: their ~L3/HBM latency hides under the
    // ~500-cycle IoU VALU loop below. +20 VGPR live range, no spill expected.
    const float* cp0 = cls_preds + ((size_t)b * kA + ab) * kC;
    float4 cv[kF4PerThread];
#pragma unroll
    for (int i = 0; i < kF4PerThread; ++i)
        cv[i] = *(const float4*)(cp0 + (i * kBlock + threadIdx.x) * 4);

    // ---- Phase 1: IoU argmax for this thread's anchor ----
    const float ax1  = an.x - an.z * 0.5f;
    const float ay1  = an.y - an.w * 0.5f;
    const float ax2p = an.x + an.z * 0.5f + 1.0f;
    const float ay2p = an.y + an.w * 0.5f + 1.0f;
    const float aarea = (ax2p - ax1) * (ay2p - ay1);

    float best = -1.0f;
    int   mid  = 0;
#pragma unroll
    for (int m = 0; m < kM; ++m) {
        float4 q = sbox[m];
        float lx = fmaxf(ax1,  q.x);
        float ly = fmaxf(ay1,  q.y);
        float rx = fminf(ax2p, q.z);
        float ry = fminf(ay2p, q.w);
        float w  = fmaxf(rx - lx, 0.0f);
        float h  = fmaxf(ry - ly, 0.0f);
        float inter = w * h;
        float uni   = aarea + sarea[m] - inter;
        float iou   = inter * __builtin_amdgcn_rcpf(uni);
        if (iou > best) { best = iou; mid = m; }
    }

    const bool pos = best >= 0.5f;
    const bool ign = (best > 0.4f) && !pos;

    float loc_sum = 0.0f, cls_sum = 0.0f, npos = 0.0f;
    if (pos) {
        npos = 1.0f;
        // exec-masked: only positive lanes (~ few %) fetch their loc row
        const float4 lp = *(const float4*)(loc_preds + ((size_t)b * kA + a) * 4);
        float4 mb = sxywh[mid];
        float ltx = (mb.x - an.x) * __builtin_amdgcn_rcpf(an.z);
        float lty = (mb.y - an.y) * __builtin_amdgcn_rcpf(an.w);
        float ltw = __logf(mb.z * __builtin_amdgcn_rcpf(an.z));
        float lth = __logf(mb.w * __builtin_amdgcn_rcpf(an.w));
        loc_sum = smooth_l1(lp.x - ltx) + smooth_l1(lp.y - lty) +
                  smooth_l1(lp.z - ltw) + smooth_l1(lp.w - lth);
        // focal correction for the target class: stream adds 0.75*f0(x_c),
        // true contribution is 0.25*f0(-x_c).
        const int   c = slab[mid];
        const float x = cls_preds[((size_t)b * kA + a) * kC + c];
        cls_sum = 0.25f * focal0(-x) - 0.75f * focal0(x);
    }
    slive[threadIdx.x] = ign ? 0.0f : 1.0f;
    __syncthreads();

    // ---- Phase 2: target-free focal stream over the block's cls slab ----
    // No per-element class compare; just a per-anchor live flag.
    float stream = 0.0f;
#pragma unroll
    for (int i = 0; i < kF4PerThread; ++i) {
        const int f  = i * kBlock + threadIdx.x;
        const int al = f / 5;                 // anchor local (magic-mul, 3 insts)
        const float live = slive[al];
        float4 v = cv[i];
        stream += live * (focal0(v.x) + focal0(v.y) + focal0(v.z) + focal0(v.w));
    }
    cls_sum += 0.75f * stream;

    // ---- Reduce: wave shuffle -> LDS -> per-block partial (no atomics) ----
#pragma unroll
    for (int off = 32; off > 0; off >>= 1) {
        loc_sum += __shfl_down(loc_sum, off);
        cls_sum += __shfl_down(cls_sum, off);
        npos    += __shfl_down(npos, off);
    }
    const int lane = threadIdx.x & 63;
    const int wid  = threadIdx.x >> 6;
    if (lane == 0) {
        sred[0][wid] = loc_sum;
        sred[1][wid] = cls_sum;
        sred[2][wid] = npos;
    }
    __syncthreads();
    if (threadIdx.x == 0) {
        float l = 0.0f, c = 0.0f, n = 0.0f;
#pragma unroll
        for (int i = 0; i < kBlock / 64; ++i) {
            l += sred[0][i]; c += sred[1][i]; n += sred[2][i];
        }
        const int bid = blockIdx.y * gridDim.x + blockIdx.x;
        partial[3 * bid + 0] = l;
        partial[3 * bid + 1] = c;
        partial[3 * bid + 2] = n;
    }
}

__global__ __launch_bounds__(1024) void retina_final(
    const float* __restrict__ partial, float* __restrict__ out)
{
    __shared__ float s[3][16];
    float l = 0.0f, c = 0.0f, n = 0.0f;
    for (int i = threadIdx.x; i < kNBlocks; i += 1024) {
        l += partial[3 * i + 0];
        c += partial[3 * i + 1];
        n += partial[3 * i + 2];
    }
#pragma unroll
    for (int off = 32; off > 0; off >>= 1) {
        l += __shfl_down(l, off);
        c += __shfl_down(c, off);
        n += __shfl_down(n, off);
    }
    const int lane = threadIdx.x & 63;
    const int wid  = threadIdx.x >> 6;
    if (lane == 0) { s[0][wid] = l; s[1][wid] = c; s[2][wid] = n; }
    __syncthreads();
    if (threadIdx.x == 0) {
        float L = 0.0f, C = 0.0f, N = 0.0f;
#pragma unroll
        for (int i = 0; i < 16; ++i) { L += s[0][i]; C += s[1][i]; N += s[2][i]; }
        float np  = fmaxf(1.0f, N);
        float inv = 1.0f / np;
        out[0] = (L + C) * inv;
        out[1] = L * inv;
        out[2] = C * inv;
    }
}

}  // namespace

extern "C" void kernel_launch(void* const* d_in, const int* in_sizes, int n_in,
                              void* d_out, int out_size, void* d_ws, size_t ws_size,
                              hipStream_t stream) {
    const float* loc_preds = (const float*)d_in[0];
    const float* cls_preds = (const float*)d_in[1];
    const float* iou_boxes = (const float*)d_in[2];
    const float* targets   = (const float*)d_in[3];
    float* out     = (float*)d_out;
    float* partial = (float*)d_ws;   // 4096*3 floats, fully overwritten each call

    dim3 grid(kGridX, kB);
    retina_main<<<grid, kBlock, 0, stream>>>(loc_preds, cls_preds, iou_boxes, targets, partial);
    retina_final<<<1, 1024, 0, stream>>>(partial, out);
}